// Round 7
// baseline (302.635 us; speedup 1.0000x reference)
//
#include <hip/hip_runtime.h>

#define LSEQ 512
#define RCA 3.8f

// Affine 4x4 with implicit bottom row (0,0,0,1), stored as 3x4.
struct Aff { float m[3][4]; };

__device__ __forceinline__ Aff compose(const Aff& A, const Aff& B) {
    Aff C;
#pragma unroll
    for (int i = 0; i < 3; ++i) {
#pragma unroll
        for (int j = 0; j < 4; ++j) {
            float v = A.m[i][0] * B.m[0][j] + A.m[i][1] * B.m[1][j] + A.m[i][2] * B.m[2][j];
            if (j == 3) v += A.m[i][3];
            C.m[i][j] = v;
        }
    }
    return C;
}

__device__ __forceinline__ Aff shflUp(const Aff& a, int d) {
    Aff r;
#pragma unroll
    for (int i = 0; i < 3; ++i)
#pragma unroll
        for (int j = 0; j < 4; ++j)
            r.m[i][j] = __shfl_up(a.m[i][j], d, 64);
    return r;
}

__device__ __forceinline__ Aff makeB(float ca, float sa, float cb, float sb) {
    Aff B;
    B.m[0][0] = ca;  B.m[0][1] = -sa * cb; B.m[0][2] =  sa * sb; B.m[0][3] = RCA * ca;
    B.m[1][0] = sa;  B.m[1][1] =  ca * cb; B.m[1][2] = -ca * sb; B.m[1][3] = RCA * sa;
    B.m[2][0] = 0.f; B.m[2][1] =  sb;      B.m[2][2] =  cb;      B.m[2][3] = 0.f;
    return B;
}

// One block (512 threads = 8 waves) per batch. Thread tid owns l = tid.
// F layout: F[((b*512+l)*24) + ch*12 + row*4 + col], ch=0 -> Fa, ch=1 -> Fb.
__global__ __launch_bounds__(512) void scan_kernel(const float* __restrict__ angles,
                                                   float* __restrict__ F) {
    const int b = blockIdx.x;
    const int tid = threadIdx.x;   // = l
    const int lane = tid & 63;
    const int w = tid >> 6;

    __shared__ float sT[8][12];    // per-wave inclusive totals

    const float a  = angles[(size_t)b * 1024 + tid];
    const float be = angles[(size_t)b * 1024 + 512 + tid];
    float sa, ca, sb, cb;
    __sincosf(a, &sa, &ca);
    __sincosf(be, &sb, &cb);

    // wave-inclusive scan of single matrices
    Aff S = makeB(ca, sa, cb, sb);
#pragma unroll
    for (int d = 1; d < 64; d <<= 1) {
        Aff o = shflUp(S, d);
        if (lane >= d) S = compose(o, S);
    }

    if (lane == 63) {
#pragma unroll
        for (int k = 0; k < 12; ++k) sT[w][k] = S.m[k / 4][k % 4];
    }
    __syncthreads();

    // exclusive cross-wave prefix E_w = T_0 @ ... @ T_{w-1}
    Aff E;
#pragma unroll
    for (int i = 0; i < 3; ++i)
#pragma unroll
        for (int j = 0; j < 4; ++j) E.m[i][j] = (i == j) ? 1.f : 0.f;
    for (int k = 0; k < w; ++k) {
        Aff T;
#pragma unroll
        for (int q = 0; q < 12; ++q) T.m[q / 4][q % 4] = sT[k][q];
        E = compose(E, T);
    }

    const Aff Sp = shflUp(S, 1);
    const Aff M = compose(E, S);                      // inclusive prefix at l
    Aff Mprev;
    if (lane == 0) Mprev = E;
    else           Mprev = compose(E, Sp);            // inclusive prefix at l-1

    // ---- epilogue: Fa/Fb = Mprev @ dB @ Minv ----
    float Rt[3][3], ti[3];
#pragma unroll
    for (int i = 0; i < 3; ++i)
#pragma unroll
        for (int j = 0; j < 3; ++j) Rt[i][j] = M.m[j][i];
#pragma unroll
    for (int i = 0; i < 3; ++i)
        ti[i] = -(M.m[0][i] * M.m[0][3] + M.m[1][i] * M.m[1][3] + M.m[2][i] * M.m[2][3]);

    float d0[4] = {-sa, -ca * cb,  ca * sb, -RCA * sa};
    float d1[4] = { ca, -sa * cb,  sa * sb,  RCA * ca};
    float e01 =  sa * sb, e02 =  sa * cb;
    float e11 = -ca * sb, e12 = -ca * cb;
    float e21 =  cb,      e22 = -sb;

    float Ga[3][4], Gb[3][4];
#pragma unroll
    for (int i = 0; i < 3; ++i) {
        float p0 = Mprev.m[i][0], p1 = Mprev.m[i][1], p2 = Mprev.m[i][2];
#pragma unroll
        for (int j = 0; j < 4; ++j) Ga[i][j] = p0 * d0[j] + p1 * d1[j];
        Gb[i][0] = 0.f;
        Gb[i][1] = p0 * e01 + p1 * e11 + p2 * e21;
        Gb[i][2] = p0 * e02 + p1 * e12 + p2 * e22;
        Gb[i][3] = 0.f;
    }

    float W[24];
#pragma unroll
    for (int i = 0; i < 3; ++i) {
#pragma unroll
        for (int j = 0; j < 3; ++j) {
            W[i * 4 + j]      = Ga[i][0] * Rt[0][j] + Ga[i][1] * Rt[1][j] + Ga[i][2] * Rt[2][j];
            W[12 + i * 4 + j] = Gb[i][0] * Rt[0][j] + Gb[i][1] * Rt[1][j] + Gb[i][2] * Rt[2][j];
        }
        W[i * 4 + 3]      = Ga[i][0] * ti[0] + Ga[i][1] * ti[1] + Ga[i][2] * ti[2] + Ga[i][3];
        W[12 + i * 4 + 3] = Gb[i][0] * ti[0] + Gb[i][1] * ti[1] + Gb[i][2] * ti[2] + Gb[i][3];
    }

    float4* w4 = reinterpret_cast<float4*>(F + ((size_t)b * LSEQ + tid) * 24);
    const float4* s4 = reinterpret_cast<const float4*>(W);
#pragma unroll
    for (int q = 0; q < 6; ++q) w4[q] = s4[q];
}

// Flat emit: out is [b][ch][l][m][c] fp32, 1,575,936 floats per batch.
// grid (1539, 32) x 256 threads; each thread writes exactly one aligned float4.
__global__ __launch_bounds__(256) void emit_flat(const float* __restrict__ F,
                                                 const float* __restrict__ coords,
                                                 const int* __restrict__ lens,
                                                 float* __restrict__ out) {
    const int b = blockIdx.y;
    const unsigned o = (blockIdx.x * 256u + threadIdx.x) * 4u;  // float index in batch

    const unsigned len = (unsigned)lens[b];
    const float* __restrict__ Cb = coords + (size_t)b * 1539;
    const float* __restrict__ Fb = F + (size_t)b * LSEQ * 24;

    // decode first element: o = ch*787968 + l*1539 + m*3 + c
    unsigned ch = (o >= 787968u) ? 1u : 0u;
    unsigned r2 = o - ch * 787968u;
    unsigned l  = r2 / 1539u;
    unsigned r3 = r2 - l * 1539u;
    unsigned m  = r3 / 3u;
    unsigned c  = r3 - m * 3u;

    float v[4];
#pragma unroll
    for (int k = 0; k < 4; ++k) {
        const float4 f = *reinterpret_cast<const float4*>(Fb + (l * 24u + ch * 12u + c * 4u));
        const float x = Cb[m * 3u];
        const float y = Cb[m * 3u + 1u];
        const float z = Cb[m * 3u + 2u];
        const bool act = (m > l) & (l < len) & (m <= len);
        const float s = act ? 1.f : 0.f;
        v[k] = s * (f.x * x + f.y * y + f.z * z + f.w);

        // carry-chain increment to next flat element
        if (++c == 3u) {
            c = 0u;
            if (++m == 513u) {
                m = 0u;
                if (++l == 512u) { l = 0u; ++ch; }
            }
        }
    }

    float4 r; r.x = v[0]; r.y = v[1]; r.z = v[2]; r.w = v[3];
    *reinterpret_cast<float4*>(out + (size_t)b * 1575936u + o) = r;
}

extern "C" void kernel_launch(void* const* d_in, const int* in_sizes, int n_in,
                              void* d_out, int out_size, void* d_ws, size_t ws_size,
                              hipStream_t stream) {
    const float* angles = (const float*)d_in[0];   // fp32 (32, 2, 512)
    const float* coords = (const float*)d_in[1];   // fp32 (32, 1539)
    const int*   lens   = (const int*)d_in[2];     // int32 (32,)
    float* out = (float*)d_out;                    // fp32 output
    float* F = (float*)d_ws;                       // 32*512*24 fp32 = 1.57 MB scratch

    scan_kernel<<<32, 512, 0, stream>>>(angles, F);
    emit_flat<<<dim3(1539, 32), 256, 0, stream>>>(F, coords, lens, out);
}

// Round 8
// 208.478 us; speedup vs baseline: 1.4516x; 1.4516x over previous
//
#include <hip/hip_runtime.h>

#define LSEQ 512
#define RCA 3.8f

// Affine 4x4 with implicit bottom row (0,0,0,1), stored as 3x4.
struct Aff { float m[3][4]; };

__device__ __forceinline__ Aff compose(const Aff& A, const Aff& B) {
    Aff C;
#pragma unroll
    for (int i = 0; i < 3; ++i) {
#pragma unroll
        for (int j = 0; j < 4; ++j) {
            float v = A.m[i][0] * B.m[0][j] + A.m[i][1] * B.m[1][j] + A.m[i][2] * B.m[2][j];
            if (j == 3) v += A.m[i][3];
            C.m[i][j] = v;
        }
    }
    return C;
}

__device__ __forceinline__ Aff shflUp(const Aff& a, int d) {
    Aff r;
#pragma unroll
    for (int i = 0; i < 3; ++i)
#pragma unroll
        for (int j = 0; j < 4; ++j)
            r.m[i][j] = __shfl_up(a.m[i][j], d, 64);
    return r;
}

__device__ __forceinline__ Aff makeB(float ca, float sa, float cb, float sb) {
    Aff B;
    B.m[0][0] = ca;  B.m[0][1] = -sa * cb; B.m[0][2] =  sa * sb; B.m[0][3] = RCA * ca;
    B.m[1][0] = sa;  B.m[1][1] =  ca * cb; B.m[1][2] = -ca * sb; B.m[1][3] = RCA * sa;
    B.m[2][0] = 0.f; B.m[2][1] =  sb;      B.m[2][2] =  cb;      B.m[2][3] = 0.f;
    return B;
}

// One block (512 threads = 8 waves) per batch. Thread tid owns l = tid.
// F layout: F[((b*512+l)*24) + ch*12 + row*4 + col], ch=0 -> Fa, ch=1 -> Fb.
__global__ __launch_bounds__(512) void scan_kernel(const float* __restrict__ angles,
                                                   float* __restrict__ F) {
    const int b = blockIdx.x;
    const int tid = threadIdx.x;   // = l
    const int lane = tid & 63;
    const int w = tid >> 6;

    __shared__ float sT[8][12];    // per-wave inclusive totals

    const float a  = angles[(size_t)b * 1024 + tid];
    const float be = angles[(size_t)b * 1024 + 512 + tid];
    float sa, ca, sb, cb;
    __sincosf(a, &sa, &ca);
    __sincosf(be, &sb, &cb);

    // wave-inclusive scan of single matrices
    Aff S = makeB(ca, sa, cb, sb);
#pragma unroll
    for (int d = 1; d < 64; d <<= 1) {
        Aff o = shflUp(S, d);
        if (lane >= d) S = compose(o, S);
    }

    if (lane == 63) {
#pragma unroll
        for (int k = 0; k < 12; ++k) sT[w][k] = S.m[k / 4][k % 4];
    }
    __syncthreads();

    // exclusive cross-wave prefix E_w = T_0 @ ... @ T_{w-1}
    Aff E;
#pragma unroll
    for (int i = 0; i < 3; ++i)
#pragma unroll
        for (int j = 0; j < 4; ++j) E.m[i][j] = (i == j) ? 1.f : 0.f;
    for (int k = 0; k < w; ++k) {
        Aff T;
#pragma unroll
        for (int q = 0; q < 12; ++q) T.m[q / 4][q % 4] = sT[k][q];
        E = compose(E, T);
    }

    const Aff Sp = shflUp(S, 1);
    const Aff M = compose(E, S);                      // inclusive prefix at l
    Aff Mprev;
    if (lane == 0) Mprev = E;
    else           Mprev = compose(E, Sp);            // inclusive prefix at l-1

    // ---- epilogue: Fa/Fb = Mprev @ dB @ Minv ----
    float Rt[3][3], ti[3];
#pragma unroll
    for (int i = 0; i < 3; ++i)
#pragma unroll
        for (int j = 0; j < 3; ++j) Rt[i][j] = M.m[j][i];
#pragma unroll
    for (int i = 0; i < 3; ++i)
        ti[i] = -(M.m[0][i] * M.m[0][3] + M.m[1][i] * M.m[1][3] + M.m[2][i] * M.m[2][3]);

    float d0[4] = {-sa, -ca * cb,  ca * sb, -RCA * sa};
    float d1[4] = { ca, -sa * cb,  sa * sb,  RCA * ca};
    float e01 =  sa * sb, e02 =  sa * cb;
    float e11 = -ca * sb, e12 = -ca * cb;
    float e21 =  cb,      e22 = -sb;

    float Ga[3][4], Gb[3][4];
#pragma unroll
    for (int i = 0; i < 3; ++i) {
        float p0 = Mprev.m[i][0], p1 = Mprev.m[i][1], p2 = Mprev.m[i][2];
#pragma unroll
        for (int j = 0; j < 4; ++j) Ga[i][j] = p0 * d0[j] + p1 * d1[j];
        Gb[i][0] = 0.f;
        Gb[i][1] = p0 * e01 + p1 * e11 + p2 * e21;
        Gb[i][2] = p0 * e02 + p1 * e12 + p2 * e22;
        Gb[i][3] = 0.f;
    }

    float W[24];
#pragma unroll
    for (int i = 0; i < 3; ++i) {
#pragma unroll
        for (int j = 0; j < 3; ++j) {
            W[i * 4 + j]      = Ga[i][0] * Rt[0][j] + Ga[i][1] * Rt[1][j] + Ga[i][2] * Rt[2][j];
            W[12 + i * 4 + j] = Gb[i][0] * Rt[0][j] + Gb[i][1] * Rt[1][j] + Gb[i][2] * Rt[2][j];
        }
        W[i * 4 + 3]      = Ga[i][0] * ti[0] + Ga[i][1] * ti[1] + Ga[i][2] * ti[2] + Ga[i][3];
        W[12 + i * 4 + 3] = Gb[i][0] * ti[0] + Gb[i][1] * ti[1] + Gb[i][2] * ti[2] + Gb[i][3];
    }

    float4* w4 = reinterpret_cast<float4*>(F + ((size_t)b * LSEQ + tid) * 24);
    const float4* s4 = reinterpret_cast<const float4*>(W);
#pragma unroll
    for (int q = 0; q < 6; ++q) w4[q] = s4[q];
}

// grid (64, 32), block 256. Block handles l = 8*bx .. 8*bx+7 for batch by.
// Compute into LDS row buffers, then drain as aligned dwordx4 streams.
__global__ __launch_bounds__(256) void emit_kernel(const float* __restrict__ F,
                                                   const float* __restrict__ coords,
                                                   const int* __restrict__ lens,
                                                   float* __restrict__ out) {
    const int b = blockIdx.y;
    const int l0 = blockIdx.x * 8;
    const int tid = threadIdx.x;

    __shared__ float sF[192];
    __shared__ float sA[1544];
    __shared__ float sB[1544];

    if (tid < 192) sF[tid] = F[((size_t)b * LSEQ + l0) * 24 + tid];

    const int len = lens[b];
    const float* cp = coords + (size_t)b * 1539;

    // coords in registers, reused across 8 rows
    const int m0 = tid, m1 = tid + 256, m2 = tid + 512;
    const float cx0 = cp[m0 * 3], cy0 = cp[m0 * 3 + 1], cz0 = cp[m0 * 3 + 2];
    const float cx1 = cp[m1 * 3], cy1 = cp[m1 * 3 + 1], cz1 = cp[m1 * 3 + 2];
    const bool has2 = (m2 < 513);
    float cx2 = 0.f, cy2 = 0.f, cz2 = 0.f;
    if (has2) { cx2 = cp[m2 * 3]; cy2 = cp[m2 * 3 + 1]; cz2 = cp[m2 * 3 + 2]; }

    __syncthreads();   // sF ready

#pragma unroll 1
    for (int i = 0; i < 8; ++i) {
        const int l = l0 + i;
        const float* f = sF + i * 24;
        const float f00 = f[0],  f01 = f[1],  f02 = f[2],  f03 = f[3];
        const float f10 = f[4],  f11 = f[5],  f12 = f[6],  f13 = f[7];
        const float f20 = f[8],  f21 = f[9],  f22 = f[10], f23 = f[11];
        const float g00 = f[12], g01 = f[13], g02 = f[14], g03 = f[15];
        const float g10 = f[16], g11 = f[17], g12 = f[18], g13 = f[19];
        const float g20 = f[20], g21 = f[21], g22 = f[22], g23 = f[23];

        const bool rowActive = (l < len);
        // row global base (floats): rbA = (b*2*512 + l)*1539 ; phase = rbA % 4 = (3l)%4
        const unsigned phase = (3u * (unsigned)l) & 3u;
        const unsigned head  = (4u - phase) & 3u;       // scalar floats before first aligned 16B
        const unsigned pad   = phase;                   // shift LDS so (pad+head) % 4 == 0

        auto cw = [&](int m, float x, float y, float z) {
            const float s = (rowActive && (m > l) && (m <= len)) ? 1.f : 0.f;
            const int base = pad + m * 3;
            sA[base + 0] = s * (f00 * x + f01 * y + f02 * z + f03);
            sA[base + 1] = s * (f10 * x + f11 * y + f12 * z + f13);
            sA[base + 2] = s * (f20 * x + f21 * y + f22 * z + f23);
            sB[base + 0] = s * (g00 * x + g01 * y + g02 * z + g03);
            sB[base + 1] = s * (g10 * x + g11 * y + g12 * z + g13);
            sB[base + 2] = s * (g20 * x + g21 * y + g22 * z + g23);
        };
        cw(m0, cx0, cy0, cz0);
        cw(m1, cx1, cy1, cz1);
        if (has2) cw(m2, cx2, cy2, cz2);
        __syncthreads();   // rows computed

        const size_t rbA = ((size_t)(b * 2) * LSEQ + l) * 1539;
        const size_t rbB = rbA + (size_t)LSEQ * 1539;
        const unsigned n4   = (1539u - head) >> 2;      // = 384
        const unsigned tail = 1539u - head - n4 * 4u;

        if (tid < (int)head) {
            out[rbA + tid] = sA[pad + tid];
            out[rbB + tid] = sB[pad + tid];
        }
        if (tid < (int)tail) {
            const unsigned off = head + n4 * 4u + tid;
            out[rbA + off] = sA[pad + off];
            out[rbB + off] = sB[pad + off];
        }
        for (unsigned k = tid; k < n4; k += 256) {
            const unsigned off = head + 4u * k;         // (rbA+off)%4 == 0, (pad+off)%4 == 0
            const float4 va = *reinterpret_cast<const float4*>(sA + pad + off);
            const float4 vb = *reinterpret_cast<const float4*>(sB + pad + off);
            *reinterpret_cast<float4*>(out + rbA + off) = va;
            *reinterpret_cast<float4*>(out + rbB + off) = vb;
        }
        __syncthreads();   // buffer free for next row
    }
}

extern "C" void kernel_launch(void* const* d_in, const int* in_sizes, int n_in,
                              void* d_out, int out_size, void* d_ws, size_t ws_size,
                              hipStream_t stream) {
    const float* angles = (const float*)d_in[0];   // fp32 (32, 2, 512)
    const float* coords = (const float*)d_in[1];   // fp32 (32, 1539)
    const int*   lens   = (const int*)d_in[2];     // int32 (32,)
    float* out = (float*)d_out;                    // fp32 output
    float* F = (float*)d_ws;                       // 32*512*24 fp32 = 1.57 MB scratch

    scan_kernel<<<32, 512, 0, stream>>>(angles, F);
    emit_kernel<<<dim3(64, 32), 256, 0, stream>>>(F, coords, lens, out);
}